// Round 1
// baseline (2397.775 us; speedup 1.0000x reference)
//
#include <hip/hip_runtime.h>
#include <math.h>

#define BB 8
#define CCH 256
#define HWN 4096
#define RR 16

// ---------------- K1: avg+max pool over spatial, per (b,c) ----------------
__global__ __launch_bounds__(256) void k_pool(const float* __restrict__ x,
                                              float* __restrict__ avgp,
                                              float* __restrict__ maxp) {
    int bc = blockIdx.x;
    const float4* p = (const float4*)(x + (size_t)bc * HWN);
    int t = threadIdx.x;
    float s = 0.f, m = -INFINITY;
#pragma unroll
    for (int i = 0; i < 4; ++i) {
        float4 v = p[t + 256 * i];
        s += v.x + v.y + v.z + v.w;
        m = fmaxf(m, fmaxf(fmaxf(v.x, v.y), fmaxf(v.z, v.w)));
    }
    for (int off = 32; off; off >>= 1) {
        s += __shfl_down(s, off);
        m = fmaxf(m, __shfl_down(m, off));
    }
    __shared__ float ss[4], sm[4];
    int wid = t >> 6;
    if ((t & 63) == 0) { ss[wid] = s; sm[wid] = m; }
    __syncthreads();
    if (t == 0) {
        float S = ss[0] + ss[1] + ss[2] + ss[3];
        float M = fmaxf(fmaxf(sm[0], sm[1]), fmaxf(sm[2], sm[3]));
        avgp[bc] = S * (1.f / (float)HWN);
        maxp[bc] = M;
    }
}

// ---------------- K2: SE gate: sigmoid(w2@relu(w1@avg) + w2@relu(w1@max)) ----------------
__global__ __launch_bounds__(256) void k_gate(const float* __restrict__ avgp,
                                              const float* __restrict__ maxp,
                                              const float* __restrict__ w1,
                                              const float* __restrict__ w2,
                                              float* __restrict__ gate) {
    int b = blockIdx.x, t = threadIdx.x;
    __shared__ float sa[CCH], sx[CCH], sh[32];
    sa[t] = avgp[b * CCH + t];
    sx[t] = maxp[b * CCH + t];
    __syncthreads();
    if (t < 32) {
        int r = t & 15;
        const float* src = (t < 16) ? sa : sx;
        float h = 0.f;
        for (int c = 0; c < CCH; ++c) h += w1[r * CCH + c] * src[c];
        sh[t] = fmaxf(h, 0.f);
    }
    __syncthreads();
    float g = 0.f;
#pragma unroll
    for (int r = 0; r < RR; ++r) g += w2[t * RR + r] * (sh[r] + sh[16 + r]);
    gate[b * CCH + t] = 1.f / (1.f + __expf(-g));
}

// ---------------- K3: xg = x * gate  (written into d_out) ----------------
__global__ __launch_bounds__(256) void k_scale(const float* __restrict__ x,
                                               const float* __restrict__ gate,
                                               float* __restrict__ xg) {
    int idx = blockIdx.x * 256 + threadIdx.x;  // float4 index
    int e = idx * 4;
    int c = (e >> 12) & 255;
    int b = e >> 20;
    float g = gate[b * CCH + c];
    float4 v = ((const float4*)x)[idx];
    v.x *= g; v.y *= g; v.z *= g; v.w *= g;
    ((float4*)xg)[idx] = v;
}

// ---------------- K4: q,k = W@xg + b   [b][16][4096] ----------------
__global__ __launch_bounds__(256) void k_qk(const float* __restrict__ xg,
                                            const float* __restrict__ qw,
                                            const float* __restrict__ qb,
                                            const float* __restrict__ kw,
                                            const float* __restrict__ kb,
                                            float* __restrict__ q,
                                            float* __restrict__ k) {
    int b = blockIdx.x >> 4;
    int n0 = (blockIdx.x & 15) * 256;
    int t = threadIdx.x;
    __shared__ float swq[RR * CCH], swk[RR * CCH];
#pragma unroll
    for (int i = 0; i < 16; ++i) {
        swq[t + 256 * i] = qw[t + 256 * i];
        swk[t + 256 * i] = kw[t + 256 * i];
    }
    __syncthreads();
    int n = n0 + t;
    float aq[RR], ak[RR];
#pragma unroll
    for (int r = 0; r < RR; ++r) { aq[r] = 0.f; ak[r] = 0.f; }
    const float* xp = xg + (size_t)b * CCH * HWN + n;
    for (int c = 0; c < CCH; ++c) {
        float xv = xp[(size_t)c * HWN];
#pragma unroll
        for (int r = 0; r < RR; ++r) {
            aq[r] += swq[r * CCH + c] * xv;
            ak[r] += swk[r * CCH + c] * xv;
        }
    }
#pragma unroll
    for (int r = 0; r < RR; ++r) {
        q[((size_t)b * RR + r) * HWN + n] = aq[r] + qb[r];
        k[((size_t)b * RR + r) * HWN + n] = ak[r] + kb[r];
    }
}

// ---------------- K5: vt[b][n][c] = (v_w @ xg)[c][n] + v_b[c]  (transposed V) ----------------
__global__ __launch_bounds__(256) void k_vt(const float* __restrict__ xg,
                                            const float* __restrict__ vw,
                                            const float* __restrict__ vb,
                                            float* __restrict__ vt) {
    int bid = blockIdx.x;
    int ct = bid & 3;
    int nt = (bid >> 2) & 63;
    int b = bid >> 8;
    int c0 = ct * 64, n0 = nt * 64;
    int t = threadIdx.x;
    int tc = t & 15, tn = t >> 4;
    __shared__ float xs[16][68];
    __shared__ float wv[64][17];
    float acc[4][4] = {};
    for (int cc0 = 0; cc0 < CCH; cc0 += 16) {
        __syncthreads();
#pragma unroll
        for (int it = 0; it < 4; ++it) {
            int idx = it * 256 + t;
            int r = idx >> 6, nn = idx & 63;
            xs[r][nn] = xg[((size_t)b * CCH + cc0 + r) * HWN + n0 + nn];
            int ci = idx >> 4, r16 = idx & 15;
            wv[ci][r16] = vw[(c0 + ci) * CCH + cc0 + r16];
        }
        __syncthreads();
#pragma unroll
        for (int r = 0; r < 16; ++r) {
            float4 a = *(const float4*)&xs[r][tn * 4];
            float av[4] = {a.x, a.y, a.z, a.w};
            float bj[4];
#pragma unroll
            for (int j = 0; j < 4; ++j) bj[j] = wv[tc * 4 + j][r];
#pragma unroll
            for (int i = 0; i < 4; ++i)
#pragma unroll
                for (int j = 0; j < 4; ++j)
                    acc[i][j] = fmaf(av[i], bj[j], acc[i][j]);
        }
    }
#pragma unroll
    for (int i = 0; i < 4; ++i) {
        float4 o;
        o.x = acc[i][0] + vb[c0 + tc * 4 + 0];
        o.y = acc[i][1] + vb[c0 + tc * 4 + 1];
        o.z = acc[i][2] + vb[c0 + tc * 4 + 2];
        o.w = acc[i][3] + vb[c0 + tc * 4 + 3];
        *(float4*)&vt[((size_t)b * HWN + n0 + tn * 4 + i) * CCH + c0 + tc * 4] = o;
    }
}

// ---------------- K6: flash attention + epilogue gamma*o/l + xg ----------------
__global__ __launch_bounds__(256) void k_attn(const float* __restrict__ q,
                                              const float* __restrict__ k,
                                              const float* __restrict__ vt,
                                              const float* __restrict__ gamma,
                                              float* __restrict__ out) {
    int bid = blockIdx.x;
    int b = bid >> 6;
    int i0 = (bid & 63) * 64;
    int t = threadIdx.x;
    int tx = t & 15, ty = t >> 4;  // ty -> i-group (4 i's), tx -> c-group (16 c's)

    __shared__ float q_s[16][64];
    __shared__ float k_s[16][64];
    __shared__ float s_tmp[64][65];
    __shared__ float p_t[64][68];
    __shared__ float m_s[64], l_s[64], al_s[64];

    {
        int d = t >> 6, ii = t & 63;
#pragma unroll
        for (int it = 0; it < 4; ++it)
            q_s[d + 4 * it][ii] = q[((size_t)b * RR + d + 4 * it) * HWN + i0 + ii];
    }
    if (t < 64) { m_s[t] = -INFINITY; l_s[t] = 0.f; }

    float acc[4][16];
#pragma unroll
    for (int i = 0; i < 4; ++i)
#pragma unroll
        for (int j = 0; j < 16; ++j) acc[i][j] = 0.f;

    // hoisted q fragment for score phase (i = t&63 fixed per thread)
    __syncthreads();
    int si = t & 63;
    float qr[16];
#pragma unroll
    for (int d = 0; d < 16; ++d) qr[d] = q_s[d][si];

    for (int jt = 0; jt < 64; ++jt) {
        int j0 = jt * 64;
        {
            int d = t >> 6, jj = t & 63;
#pragma unroll
            for (int it = 0; it < 4; ++it)
                k_s[d + 4 * it][jj] = k[((size_t)b * RR + d + 4 * it) * HWN + j0 + jj];
        }
        __syncthreads();  // A: k_s ready; prev PV finished (p_t safe to rewrite)

        {
            int jb = t >> 6;
#pragma unroll
            for (int w = 0; w < 16; ++w) {
                int j = jb * 16 + w;
                float s = 0.f;
#pragma unroll
                for (int d = 0; d < 16; ++d) s = fmaf(qr[d], k_s[d][j], s);
                s_tmp[si][j] = s;
            }
        }
        __syncthreads();  // B: scores ready

        if (t < 64) {
            int i = t;
            float mold = m_s[i];
            float tm = -INFINITY;
#pragma unroll 8
            for (int j = 0; j < 64; ++j) tm = fmaxf(tm, s_tmp[i][j]);
            float mnew = fmaxf(mold, tm);
            float al = __expf(mold - mnew);
            float ps = 0.f;
#pragma unroll 8
            for (int j = 0; j < 64; ++j) {
                float p = __expf(s_tmp[i][j] - mnew);
                p_t[j][i] = p;
                ps += p;
            }
            l_s[i] = l_s[i] * al + ps;
            m_s[i] = mnew;
            al_s[i] = al;
        }
        __syncthreads();  // C: p ready

        float al4[4];
#pragma unroll
        for (int i = 0; i < 4; ++i) al4[i] = al_s[ty * 4 + i];
#pragma unroll
        for (int i = 0; i < 4; ++i)
#pragma unroll
            for (int j = 0; j < 16; ++j) acc[i][j] *= al4[i];

        const float* vbase = vt + ((size_t)b * HWN + j0) * CCH + tx * 16;
        for (int kk = 0; kk < 64; ++kk) {
            float pf[4];
            *(float4*)pf = *(const float4*)&p_t[kk][ty * 4];
            float vf[16];
            const float4* vp = (const float4*)(vbase + (size_t)kk * CCH);
#pragma unroll
            for (int u = 0; u < 4; ++u) ((float4*)vf)[u] = vp[u];
#pragma unroll
            for (int i = 0; i < 4; ++i)
#pragma unroll
                for (int j = 0; j < 16; ++j)
                    acc[i][j] = fmaf(pf[i], vf[j], acc[i][j]);
        }
        // p_t/k_s hazards handled by sync A of next iteration
    }
    __syncthreads();

    float g = gamma[0];
    float il[4];
#pragma unroll
    for (int i = 0; i < 4; ++i) il[i] = g / l_s[ty * 4 + i];
#pragma unroll
    for (int i = 0; i < 4; ++i)
#pragma unroll
        for (int j = 0; j < 16; ++j) acc[i][j] *= il[i];

    // 4 passes: transpose [i][c]-chunks through LDS so global writes are coalesced in i
    for (int pass = 0; pass < 4; ++pass) {
        __syncthreads();
        if ((tx >> 2) == pass) {
            int cl0 = (tx & 3) * 16;
#pragma unroll
            for (int j = 0; j < 16; ++j)
#pragma unroll
                for (int i = 0; i < 4; ++i)
                    s_tmp[cl0 + j][ty * 4 + i] = acc[i][j];
        }
        __syncthreads();
        int i = t & 63, clb = t >> 6;
#pragma unroll
        for (int it = 0; it < 16; ++it) {
            int cl = clb + 4 * it;
            int c = pass * 64 + cl;
            size_t gidx = ((size_t)b * CCH + c) * HWN + i0 + i;
            out[gidx] = s_tmp[cl][i] + out[gidx];
        }
    }
}

extern "C" void kernel_launch(void* const* d_in, const int* in_sizes, int n_in,
                              void* d_out, int out_size, void* d_ws, size_t ws_size,
                              hipStream_t stream) {
    const float* x = (const float*)d_in[0];
    const float* w1 = (const float*)d_in[1];
    const float* w2 = (const float*)d_in[2];
    const float* qw = (const float*)d_in[3];
    const float* qb = (const float*)d_in[4];
    const float* kw = (const float*)d_in[5];
    const float* kb = (const float*)d_in[6];
    const float* vw = (const float*)d_in[7];
    const float* vb = (const float*)d_in[8];
    const float* gamma = (const float*)d_in[9];
    float* out = (float*)d_out;
    float* ws = (float*)d_ws;

    float* avgp = ws;              // 2048
    float* maxp = ws + 2048;       // 2048
    float* gate = ws + 4096;       // 2048
    float* q = ws + 6144;          // 524288
    float* k = ws + 530432;        // 524288
    float* vt = ws + 1054720;      // 8388608
    // total 9,443,328 floats = 37.8 MB of ws

    k_pool<<<2048, 256, 0, stream>>>(x, avgp, maxp);
    k_gate<<<8, 256, 0, stream>>>(avgp, maxp, w1, w2, gate);
    k_scale<<<8192, 256, 0, stream>>>(x, gate, out);       // xg -> d_out
    k_qk<<<128, 256, 0, stream>>>(out, qw, qb, kw, kb, q, k);
    k_vt<<<2048, 256, 0, stream>>>(out, vw, vb, vt);
    k_attn<<<512, 256, 0, stream>>>(q, k, vt, gamma, out); // overwrites d_out
}

// Round 2
// 393.069 us; speedup vs baseline: 6.1001x; 6.1001x over previous
//
#include <hip/hip_runtime.h>
#include <hip/hip_bf16.h>
#include <math.h>

#define BB 8
#define CCH 256
#define HWN 4096
#define RR 16
#define PJ 72   // p_lds row stride (bf16): 144B rows -> 16B aligned, write conflicts ~4-way only

typedef __attribute__((ext_vector_type(8))) short short8;   // 8 bf16 = one MFMA A/B frag
typedef __attribute__((ext_vector_type(4))) float f32x4;    // MFMA C/D frag

static __device__ __forceinline__ unsigned short f2bf(float x) {
    union { float f; unsigned u; } v; v.f = x;
    return (unsigned short)((v.u + 0x8000u) >> 16);   // round-half-up bf16, 2 VALU ops
}

// ---------------- K1: avg+max pool over spatial, per (b,c) ----------------
__global__ __launch_bounds__(256) void k_pool(const float* __restrict__ x,
                                              float* __restrict__ avgp,
                                              float* __restrict__ maxp) {
    int bc = blockIdx.x;
    const float4* p = (const float4*)(x + (size_t)bc * HWN);
    int t = threadIdx.x;
    float s = 0.f, m = -INFINITY;
#pragma unroll
    for (int i = 0; i < 4; ++i) {
        float4 v = p[t + 256 * i];
        s += v.x + v.y + v.z + v.w;
        m = fmaxf(m, fmaxf(fmaxf(v.x, v.y), fmaxf(v.z, v.w)));
    }
    for (int off = 32; off; off >>= 1) {
        s += __shfl_down(s, off);
        m = fmaxf(m, __shfl_down(m, off));
    }
    __shared__ float ss[4], sm[4];
    int wid = t >> 6;
    if ((t & 63) == 0) { ss[wid] = s; sm[wid] = m; }
    __syncthreads();
    if (t == 0) {
        float S = ss[0] + ss[1] + ss[2] + ss[3];
        float M = fmaxf(fmaxf(sm[0], sm[1]), fmaxf(sm[2], sm[3]));
        avgp[bc] = S * (1.f / (float)HWN);
        maxp[bc] = M;
    }
}

// ---------------- K2: SE gate ----------------
__global__ __launch_bounds__(256) void k_gate(const float* __restrict__ avgp,
                                              const float* __restrict__ maxp,
                                              const float* __restrict__ w1,
                                              const float* __restrict__ w2,
                                              float* __restrict__ gate) {
    int b = blockIdx.x, t = threadIdx.x;
    __shared__ float sa[CCH], sx[CCH], sh[32];
    sa[t] = avgp[b * CCH + t];
    sx[t] = maxp[b * CCH + t];
    __syncthreads();
    if (t < 32) {
        int r = t & 15;
        const float* src = (t < 16) ? sa : sx;
        float h = 0.f;
        for (int c = 0; c < CCH; ++c) h += w1[r * CCH + c] * src[c];
        sh[t] = fmaxf(h, 0.f);
    }
    __syncthreads();
    float g = 0.f;
#pragma unroll
    for (int r = 0; r < RR; ++r) g += w2[t * RR + r] * (sh[r] + sh[16 + r]);
    gate[b * CCH + t] = 1.f / (1.f + __expf(-g));
}

// ---------------- K3: xg = x * gate  (fp32, into d_out — residual + proj input) ----------------
__global__ __launch_bounds__(256) void k_scale(const float* __restrict__ x,
                                               const float* __restrict__ gate,
                                               float* __restrict__ xg) {
    int idx = blockIdx.x * 256 + threadIdx.x;  // float4 index
    int e = idx * 4;
    int c = (e >> 12) & 255;
    int b = e >> 20;
    float g = gate[b * CCH + c];
    float4 v = ((const float4*)x)[idx];
    v.x *= g; v.y *= g; v.z *= g; v.w *= g;
    ((float4*)xg)[idx] = v;
}

// ---------------- K4: qT,kT = (W@xg + b)^T as bf16 [b][n][16] (fragment-ready) ----------------
__global__ __launch_bounds__(256) void k_qk(const float* __restrict__ xg,
                                            const float* __restrict__ qw,
                                            const float* __restrict__ qb,
                                            const float* __restrict__ kw,
                                            const float* __restrict__ kb,
                                            unsigned short* __restrict__ qT,
                                            unsigned short* __restrict__ kT) {
    int b = blockIdx.x >> 4;
    int n0 = (blockIdx.x & 15) * 256;
    int t = threadIdx.x;
    __shared__ float swq[RR * CCH], swk[RR * CCH];
#pragma unroll
    for (int i = 0; i < 16; ++i) {
        swq[t + 256 * i] = qw[t + 256 * i];
        swk[t + 256 * i] = kw[t + 256 * i];
    }
    __syncthreads();
    int n = n0 + t;
    float aq[RR], ak[RR];
#pragma unroll
    for (int r = 0; r < RR; ++r) { aq[r] = 0.f; ak[r] = 0.f; }
    const float* xp = xg + (size_t)b * CCH * HWN + n;
    for (int c = 0; c < CCH; ++c) {
        float xv = xp[(size_t)c * HWN];
#pragma unroll
        for (int r = 0; r < RR; ++r) {
            aq[r] += swq[r * CCH + c] * xv;
            ak[r] += swk[r * CCH + c] * xv;
        }
    }
    unsigned uq[8], uk[8];
#pragma unroll
    for (int j = 0; j < 8; ++j) {
        uq[j] = (unsigned)f2bf(aq[2 * j] + qb[2 * j]) |
                ((unsigned)f2bf(aq[2 * j + 1] + qb[2 * j + 1]) << 16);
        uk[j] = (unsigned)f2bf(ak[2 * j] + kb[2 * j]) |
                ((unsigned)f2bf(ak[2 * j + 1] + kb[2 * j + 1]) << 16);
    }
    size_t base = ((size_t)b * HWN + n) * RR;  // ushort index, 32B-aligned
    uint4 q0 = {uq[0], uq[1], uq[2], uq[3]}, q1 = {uq[4], uq[5], uq[6], uq[7]};
    uint4 k0 = {uk[0], uk[1], uk[2], uk[3]}, k1 = {uk[4], uk[5], uk[6], uk[7]};
    ((uint4*)(qT + base))[0] = q0; ((uint4*)(qT + base))[1] = q1;
    ((uint4*)(kT + base))[0] = k0; ((uint4*)(kT + base))[1] = k1;
}

// ---------------- K5: vB = bf16(v_w @ xg + v_b)  [b][c][n] (natural, j-contig = A-frag-ready) ----------------
__global__ __launch_bounds__(256) void k_vt(const float* __restrict__ xg,
                                            const float* __restrict__ vw,
                                            const float* __restrict__ vb,
                                            unsigned short* __restrict__ vB) {
    int bid = blockIdx.x;
    int ct = bid & 3;
    int nt = (bid >> 2) & 63;
    int b = bid >> 8;
    int c0 = ct * 64, n0 = nt * 64;
    int t = threadIdx.x;
    int tn = t & 15, tc = t >> 4;   // tn fastest -> coalesced n-contig stores
    __shared__ float xs[16][68];
    __shared__ float wv[64][17];
    float acc[4][4] = {};
    for (int cc0 = 0; cc0 < CCH; cc0 += 16) {
        __syncthreads();
#pragma unroll
        for (int it = 0; it < 4; ++it) {
            int idx = it * 256 + t;
            int r = idx >> 6, nn = idx & 63;
            xs[r][nn] = xg[((size_t)b * CCH + cc0 + r) * HWN + n0 + nn];
            int ci = idx >> 4, r16 = idx & 15;
            wv[ci][r16] = vw[(c0 + ci) * CCH + cc0 + r16];
        }
        __syncthreads();
#pragma unroll
        for (int r = 0; r < 16; ++r) {
            float4 a = *(const float4*)&xs[r][tn * 4];
            float av[4] = {a.x, a.y, a.z, a.w};
            float bj[4];
#pragma unroll
            for (int j = 0; j < 4; ++j) bj[j] = wv[tc * 4 + j][r];
#pragma unroll
            for (int i = 0; i < 4; ++i)
#pragma unroll
                for (int j = 0; j < 4; ++j)
                    acc[i][j] = fmaf(av[i], bj[j], acc[i][j]);
        }
    }
#pragma unroll
    for (int j = 0; j < 4; ++j) {
        int c = c0 + tc * 4 + j;
        float vbias = vb[c];
        ushort4 o;
        o.x = f2bf(acc[0][j] + vbias);
        o.y = f2bf(acc[1][j] + vbias);
        o.z = f2bf(acc[2][j] + vbias);
        o.w = f2bf(acc[3][j] + vbias);
        *(ushort4*)(vB + (((size_t)b * CCH + c) << 12) + n0 + tn * 4) = o;
    }
}

// ---------------- K6: MFMA flash attention + epilogue gamma*o/l + xg ----------------
// Block = (b, 64 queries). Wave w: S rows [16w,16w+16) via 4 MFMAs (d=16 zero-padded to K=32),
// fixed-shift softmax p = exp2(s*log2e - 8*log2e) (no running max; shift cancels in p/l),
// p -> LDS bf16 -> B-frags; PV: wave w owns c-range [64w,64w+64), 32 MFMAs per j-tile.
__global__ __launch_bounds__(256) void k_attn(const unsigned short* __restrict__ qT,
                                              const unsigned short* __restrict__ kT,
                                              const unsigned short* __restrict__ vB,
                                              const float* __restrict__ gamma,
                                              float* __restrict__ out) {
    int b = blockIdx.x >> 6;
    int i0 = (blockIdx.x & 63) << 6;
    int t = threadIdx.x;
    int w = t >> 6, l = t & 63;
    int quad = l >> 4, ln = l & 15;

    __shared__ __align__(16) unsigned short p_lds[64 * PJ];
    __shared__ float l_s[64];

    const short8 zs = {0, 0, 0, 0, 0, 0, 0, 0};
    const f32x4 zf = {0.f, 0.f, 0.f, 0.f};

    // Q A-frag: A[m=ln][k=quad*8+jj], k=d (quads 2,3 = zero pad)
    short8 aq = zs;
    if (quad < 2)
        aq = *(const short8*)(qT + (((size_t)b * HWN + i0 + w * 16 + ln) << 4) + (quad << 3));

    f32x4 acc[4][4];
#pragma unroll
    for (int cs = 0; cs < 4; ++cs)
#pragma unroll
        for (int is = 0; is < 4; ++is) acc[cs][is] = zf;
    float lpart[4] = {0.f, 0.f, 0.f, 0.f};

    const float c1 = 1.44269504f;          // log2(e)
    const float c0 = -11.5415603f;         // -8*log2(e): safety shift, cancels in p/l

    const unsigned short* vrow = vB + (((size_t)b * CCH + w * 64) << 12);

    for (int jt = 0; jt < 64; ++jt) {
        int j0 = jt << 6;

        // K B-frags: B[k=quad*8+jj][n=ln], k=d (zero-padded)
        short8 bk[4];
#pragma unroll
        for (int js = 0; js < 4; ++js) {
            bk[js] = zs;
            if (quad < 2)
                bk[js] = *(const short8*)(kT + (((size_t)b * HWN + j0 + js * 16 + ln) << 4) + (quad << 3));
        }
        // prefetch V A-frags (independent of LDS; overlaps barrier wait)
        short8 av[2][4];
#pragma unroll
        for (int ks = 0; ks < 2; ++ks)
#pragma unroll
            for (int cs = 0; cs < 4; ++cs)
                av[ks][cs] = *(const short8*)(vrow + (((size_t)(cs * 16 + ln)) << 12) + j0 + ks * 32 + quad * 8);

        f32x4 sf[4];
#pragma unroll
        for (int js = 0; js < 4; ++js)
            sf[js] = __builtin_amdgcn_mfma_f32_16x16x32_bf16(aq, bk[js], zf, 0, 0, 0);

        // p = exp2(s*c1 + c0); store bf16 to LDS in C/D layout; l accumulated per-lane
#pragma unroll
        for (int js = 0; js < 4; ++js)
#pragma unroll
            for (int r = 0; r < 4; ++r) {
                float p = exp2f(fmaf(sf[js][r], c1, c0));
                lpart[r] += p;
                p_lds[(w * 16 + quad * 4 + r) * PJ + js * 16 + ln] = f2bf(p);
            }
        __syncthreads();   // p ready (all waves)

        // PV: A = V[c][j], B = P[j][i]
#pragma unroll
        for (int ks = 0; ks < 2; ++ks) {
            short8 bp[4];
#pragma unroll
            for (int is = 0; is < 4; ++is)
                bp[is] = *(const short8*)(p_lds + (is * 16 + ln) * PJ + ks * 32 + quad * 8);
#pragma unroll
            for (int cs = 0; cs < 4; ++cs)
#pragma unroll
                for (int is = 0; is < 4; ++is)
                    acc[cs][is] = __builtin_amdgcn_mfma_f32_16x16x32_bf16(av[ks][cs], bp[is], acc[cs][is], 0, 0, 0);
        }
        __syncthreads();   // PV reads done; p_lds safe to rewrite
    }

    // l: butterfly sum over the 16 lanes of each quad (rows = w*16 + quad*4 + r)
#pragma unroll
    for (int r = 0; r < 4; ++r) {
        float v = lpart[r];
        v += __shfl_xor(v, 1, 64);
        v += __shfl_xor(v, 2, 64);
        v += __shfl_xor(v, 4, 64);
        v += __shfl_xor(v, 8, 64);
        if (ln == 0) l_s[w * 16 + quad * 4 + r] = v;
    }
    __syncthreads();

    float g = gamma[0];
    float rinv[4];
#pragma unroll
    for (int is = 0; is < 4; ++is) rinv[is] = g / l_s[is * 16 + ln];

    // epilogue: out = gamma*o/l + xg (xg already in out)
    float* orow = out + (((size_t)b * CCH + w * 64) << 12) + i0;
#pragma unroll
    for (int cs = 0; cs < 4; ++cs)
#pragma unroll
        for (int r = 0; r < 4; ++r) {
            float* po = orow + ((size_t)(cs * 16 + quad * 4 + r) << 12);
#pragma unroll
            for (int is = 0; is < 4; ++is) {
                int idx = is * 16 + ln;
                po[idx] = acc[cs][is][r] * rinv[is] + po[idx];
            }
        }
}

extern "C" void kernel_launch(void* const* d_in, const int* in_sizes, int n_in,
                              void* d_out, int out_size, void* d_ws, size_t ws_size,
                              hipStream_t stream) {
    const float* x = (const float*)d_in[0];
    const float* w1 = (const float*)d_in[1];
    const float* w2 = (const float*)d_in[2];
    const float* qw = (const float*)d_in[3];
    const float* qb = (const float*)d_in[4];
    const float* kw = (const float*)d_in[5];
    const float* kb = (const float*)d_in[6];
    const float* vw = (const float*)d_in[7];
    const float* vb = (const float*)d_in[8];
    const float* gamma = (const float*)d_in[9];
    float* out = (float*)d_out;
    char* ws = (char*)d_ws;

    float* avgp = (float*)(ws);                       // 8 KB
    float* maxp = (float*)(ws + 8192);                // 8 KB
    float* gate = (float*)(ws + 16384);               // 8 KB
    unsigned short* qT = (unsigned short*)(ws + 24576);            // 1 MB  [b][n][16] bf16
    unsigned short* kT = (unsigned short*)(ws + 24576 + 1048576);  // 1 MB
    unsigned short* vB = (unsigned short*)(ws + 24576 + 2097152);  // 16.8 MB [b][c][n] bf16

    k_pool<<<2048, 256, 0, stream>>>(x, avgp, maxp);
    k_gate<<<8, 256, 0, stream>>>(avgp, maxp, w1, w2, gate);
    k_scale<<<8192, 256, 0, stream>>>(x, gate, out);            // xg (fp32) -> d_out
    k_qk<<<128, 256, 0, stream>>>(out, qw, qb, kw, kb, qT, kT);
    k_vt<<<2048, 256, 0, stream>>>(out, vw, vb, vB);
    k_attn<<<512, 256, 0, stream>>>(qT, kT, vB, gamma, out);    // overwrites d_out
}

// Round 3
// 355.841 us; speedup vs baseline: 6.7383x; 1.1046x over previous
//
#include <hip/hip_runtime.h>
#include <hip/hip_bf16.h>
#include <math.h>

#define BB 8
#define CCH 256
#define HWN 4096
#define RR 16
#define PJ 136   // p_lds ushort row stride: 272B rows, 16B-aligned, 2-way-free bank pattern

typedef __attribute__((ext_vector_type(8))) short short8;   // 8 bf16 = K=32 MFMA A/B frag
typedef __attribute__((ext_vector_type(4))) float f32x4;    // MFMA C/D frag

static __device__ __forceinline__ unsigned short f2bf(float x) {
    union { float f; unsigned u; } v; v.f = x;
    return (unsigned short)((v.u + 0x8000u) >> 16);   // round-half-up bf16
}

// ---------------- K1: avg+max pool over spatial, per (b,c) ----------------
__global__ __launch_bounds__(256) void k_pool(const float* __restrict__ x,
                                              float* __restrict__ avgp,
                                              float* __restrict__ maxp) {
    int bc = blockIdx.x;
    const float4* p = (const float4*)(x + (size_t)bc * HWN);
    int t = threadIdx.x;
    float s = 0.f, m = -INFINITY;
#pragma unroll
    for (int i = 0; i < 4; ++i) {
        float4 v = p[t + 256 * i];
        s += v.x + v.y + v.z + v.w;
        m = fmaxf(m, fmaxf(fmaxf(v.x, v.y), fmaxf(v.z, v.w)));
    }
    for (int off = 32; off; off >>= 1) {
        s += __shfl_down(s, off);
        m = fmaxf(m, __shfl_down(m, off));
    }
    __shared__ float ss[4], sm[4];
    int wid = t >> 6;
    if ((t & 63) == 0) { ss[wid] = s; sm[wid] = m; }
    __syncthreads();
    if (t == 0) {
        float S = ss[0] + ss[1] + ss[2] + ss[3];
        float M = fmaxf(fmaxf(sm[0], sm[1]), fmaxf(sm[2], sm[3]));
        avgp[bc] = S * (1.f / (float)HWN);
        maxp[bc] = M;
    }
}

// ---------------- K2: SE gate ----------------
__global__ __launch_bounds__(256) void k_gate(const float* __restrict__ avgp,
                                              const float* __restrict__ maxp,
                                              const float* __restrict__ w1,
                                              const float* __restrict__ w2,
                                              float* __restrict__ gate) {
    int b = blockIdx.x, t = threadIdx.x;
    __shared__ float sa[CCH], sx[CCH], sh[32];
    sa[t] = avgp[b * CCH + t];
    sx[t] = maxp[b * CCH + t];
    __syncthreads();
    if (t < 32) {
        int r = t & 15;
        const float* src = (t < 16) ? sa : sx;
        float h = 0.f;
        for (int c = 0; c < CCH; ++c) h += w1[r * CCH + c] * src[c];
        sh[t] = fmaxf(h, 0.f);
    }
    __syncthreads();
    float g = 0.f;
#pragma unroll
    for (int r = 0; r < RR; ++r) g += w2[t * RR + r] * (sh[r] + sh[16 + r]);
    gate[b * CCH + t] = 1.f / (1.f + __expf(-g));
}

// ---------------- K-wprep: pack [vw;qw;kw] -> Wb bf16 [288][256] ----------------
__global__ __launch_bounds__(256) void k_wprep(const float* __restrict__ vw,
                                               const float* __restrict__ qw,
                                               const float* __restrict__ kw,
                                               unsigned short* __restrict__ Wb) {
    int idx = blockIdx.x * 256 + threadIdx.x;   // 288*256 = 73728
    int m = idx >> 8, c = idx & 255;
    float v;
    if (m < 256) v = vw[idx];
    else if (m < 272) v = qw[(m - 256) * 256 + c];
    else v = kw[(m - 272) * 256 + c];
    Wb[idx] = f2bf(v);
}

// ---------------- K-proj: fused q,k,v = Wb @ (x*gate) via bf16 MFMA ----------------
// Block (b, n-tile 64), 4 waves; wave w owns n-subtile w (16 n). M=288 rows (v:0..255,
// q:256..271, k:272..287). x staged fp32 in LDS per 64-c chunk; gate applied at stage.
// Outputs: vB [b][c][n] bf16, qT/kT [b][n][16] bf16.
__global__ __launch_bounds__(256) void k_proj(const float* __restrict__ x,
                                              const float* __restrict__ gate,
                                              const unsigned short* __restrict__ Wb,
                                              const float* __restrict__ vb,
                                              const float* __restrict__ qb,
                                              const float* __restrict__ kb,
                                              unsigned short* __restrict__ qT,
                                              unsigned short* __restrict__ kT,
                                              unsigned short* __restrict__ vB) {
    int b = blockIdx.x >> 6;
    int n0 = (blockIdx.x & 63) << 6;
    int t = threadIdx.x;
    int w = t >> 6, l = t & 63, quad = l >> 4, ln = l & 15;

    __shared__ float xs[64][72];     // [c-chunk][n], stride 72 -> 2-way-free staging writes
    __shared__ float qk_s[32][66];   // q rows 0..15, k rows 16..31 (fp32, for transpose)

    const f32x4 zf = {0.f, 0.f, 0.f, 0.f};
    f32x4 acc[18];
#pragma unroll
    for (int mt = 0; mt < 18; ++mt) acc[mt] = zf;

    for (int cc = 0; cc < 4; ++cc) {
        __syncthreads();   // previous chunk's readers done
#pragma unroll
        for (int it = 0; it < 4; ++it) {
            int idx = it * 256 + t;
            int cl = idx >> 4, nq = idx & 15;
            int c = cc * 64 + cl;
            float g = gate[b * CCH + c];
            float4 v = *(const float4*)(x + (((size_t)(b * CCH + c)) << 12) + n0 + nq * 4);
            v.x *= g; v.y *= g; v.z *= g; v.w *= g;
            *(float4*)&xs[cl][nq * 4] = v;
        }
        __syncthreads();

        // B-frags: B[k = kc*32+quad*8+kk][n = w*16+ln]
        short8 bfrag[2];
#pragma unroll
        for (int kc = 0; kc < 2; ++kc) {
            short8 bf;
#pragma unroll
            for (int kk = 0; kk < 8; ++kk)
                bf[kk] = (short)f2bf(xs[kc * 32 + quad * 8 + kk][w * 16 + ln]);
            bfrag[kc] = bf;
        }
#pragma unroll
        for (int mt = 0; mt < 18; ++mt) {
#pragma unroll
            for (int kc = 0; kc < 2; ++kc) {
                short8 af = *(const short8*)(Wb + ((size_t)(mt * 16 + ln)) * 256 + cc * 64 + kc * 32 + quad * 8);
                acc[mt] = __builtin_amdgcn_mfma_f32_16x16x32_bf16(af, bfrag[kc], acc[mt], 0, 0, 0);
            }
        }
    }

    // store v rows (m-tiles 0..15): D[m=mt*16+quad*4+r][n=n0+w*16+ln]
#pragma unroll
    for (int mt = 0; mt < 16; ++mt) {
#pragma unroll
        for (int r = 0; r < 4; ++r) {
            int m = mt * 16 + quad * 4 + r;
            vB[(((size_t)(b * CCH + m)) << 12) + n0 + w * 16 + ln] = f2bf(acc[mt][r] + vb[m]);
        }
    }
    // q/k: bounce through LDS to get [n][d] layout
#pragma unroll
    for (int r = 0; r < 4; ++r) {
        qk_s[quad * 4 + r][w * 16 + ln] = acc[16][r];        // q: d = quad*4+r
        qk_s[16 + quad * 4 + r][w * 16 + ln] = acc[17][r];   // k
    }
    __syncthreads();
    if (t < 128) {
        int isK = t >> 6;
        int n = t & 63;
        const float* bias = isK ? kb : qb;
        unsigned u32[8];
#pragma unroll
        for (int j = 0; j < 8; ++j) {
            unsigned lo = f2bf(qk_s[isK * 16 + 2 * j][n] + bias[2 * j]);
            unsigned hi = f2bf(qk_s[isK * 16 + 2 * j + 1][n] + bias[2 * j + 1]);
            u32[j] = lo | (hi << 16);
        }
        unsigned short* dst = (isK ? kT : qT) + ((size_t)(b * HWN + n0 + n)) * RR;
        uint4 d0 = {u32[0], u32[1], u32[2], u32[3]};
        uint4 d1 = {u32[4], u32[5], u32[6], u32[7]};
        ((uint4*)dst)[0] = d0;
        ((uint4*)dst)[1] = d1;
    }
}

// ---------------- K-attn: MFMA flash attention, j-tile 128, dbuf P, 1 barrier/iter ----------------
// Block (b, 64 i), 4 waves. Wave w: S rows [16w,16w+16) x 128 j (8 MFMAs, d zero-padded K=32),
// fixed-shift softmax p = exp2(s*log2e - 8*log2e); P -> dbuf LDS bf16; PV: wave w owns
// c [64w,64w+64): 4cs x 4is x 4ks = 64 MFMAs/iter. V(iter) + K(iter+1) prefetched before the
// single barrier. Epilogue: out = gamma*o/l + x*gate (residual read directly from x).
__global__ __launch_bounds__(256) void k_attn(const unsigned short* __restrict__ qT,
                                              const unsigned short* __restrict__ kT,
                                              const unsigned short* __restrict__ vB,
                                              const float* __restrict__ x,
                                              const float* __restrict__ gate,
                                              const float* __restrict__ gamma,
                                              float* __restrict__ out) {
    int b = blockIdx.x >> 6;
    int i0 = (blockIdx.x & 63) << 6;
    int t = threadIdx.x;
    int w = t >> 6, l = t & 63;
    int quad = l >> 4, ln = l & 15;

    __shared__ __align__(16) unsigned short p_lds[2][64 * PJ];
    __shared__ float l_s[64];

    const short8 zs = {0, 0, 0, 0, 0, 0, 0, 0};
    const f32x4 zf = {0.f, 0.f, 0.f, 0.f};

    // Q A-frag (persistent): A[m=ln][k=quad*8+kk], k=d (quads 2,3 zero)
    short8 aq = zs;
    if (quad < 2)
        aq = *(const short8*)(qT + (((size_t)(b * HWN + i0 + w * 16 + ln)) << 4) + (quad << 3));

    f32x4 acc[4][4];
#pragma unroll
    for (int cs = 0; cs < 4; ++cs)
#pragma unroll
        for (int is = 0; is < 4; ++is) acc[cs][is] = zf;
    float lpart[4] = {0.f, 0.f, 0.f, 0.f};

    const float c1 = 1.44269504f;      // log2(e)
    const float c0 = -11.5415603f;     // -8*log2(e): fixed shift, cancels in p/l

    const unsigned short* vrow = vB + (((size_t)(b * CCH + w * 64)) << 12);
    const unsigned short* krow = kT + (((size_t)(b * HWN)) << 4);

    // K frags for iter 0 (software-pipelined)
    short8 bk[8];
#pragma unroll
    for (int jn = 0; jn < 8; ++jn) {
        bk[jn] = zs;
        if (quad < 2)
            bk[jn] = *(const short8*)(krow + (((size_t)(jn * 16 + ln)) << 4) + (quad << 3));
    }

    for (int jt = 0; jt < 32; ++jt) {
        int j0 = jt << 7;
        int buf = jt & 1;

        // prefetch V A-frags for THIS iter (drained at the barrier, covered by S+exp)
        short8 av[4][4];
#pragma unroll
        for (int ks = 0; ks < 4; ++ks)
#pragma unroll
            for (int cs = 0; cs < 4; ++cs)
                av[ks][cs] = *(const short8*)(vrow + (((size_t)(cs * 16 + ln)) << 12) + j0 + ks * 32 + quad * 8);

        // S = Q.K^T for this wave's 16 i x 128 j
        f32x4 sf[8];
#pragma unroll
        for (int jn = 0; jn < 8; ++jn)
            sf[jn] = __builtin_amdgcn_mfma_f32_16x16x32_bf16(aq, bk[jn], zf, 0, 0, 0);

        // prefetch K frags for NEXT iter (drained at barrier, used after next barrier)
        if (jt < 31) {
            int j0n = (jt + 1) << 7;
#pragma unroll
            for (int jn = 0; jn < 8; ++jn)
                if (quad < 2)
                    bk[jn] = *(const short8*)(krow + (((size_t)(j0n + jn * 16 + ln)) << 4) + (quad << 3));
        }

        // softmax (fixed shift) + P -> LDS (bf16, C/D layout rows)
#pragma unroll
        for (int jn = 0; jn < 8; ++jn)
#pragma unroll
            for (int r = 0; r < 4; ++r) {
                float p = exp2f(fmaf(sf[jn][r], c1, c0));
                lpart[r] += p;
                p_lds[buf][(w * 16 + quad * 4 + r) * PJ + jn * 16 + ln] = f2bf(p);
            }

        __syncthreads();   // the ONLY barrier: P(buf) ready; V/K prefetch drained

        // PV: A = V[c][j], B = P[j][i]
#pragma unroll
        for (int ks = 0; ks < 4; ++ks) {
            short8 bp[4];
#pragma unroll
            for (int is = 0; is < 4; ++is)
                bp[is] = *(const short8*)(p_lds[buf] + (is * 16 + ln) * PJ + ks * 32 + quad * 8);
#pragma unroll
            for (int cs = 0; cs < 4; ++cs)
#pragma unroll
                for (int is = 0; is < 4; ++is)
                    acc[cs][is] = __builtin_amdgcn_mfma_f32_16x16x32_bf16(av[ks][cs], bp[is], acc[cs][is], 0, 0, 0);
        }
        // no second barrier: next iter writes the other buffer; reads(n) are drained
        // before writes(n+2) by barrier(n+1).
    }

    // l: butterfly over the 16 lanes of each quad
#pragma unroll
    for (int r = 0; r < 4; ++r) {
        float v = lpart[r];
        v += __shfl_xor(v, 1, 64);
        v += __shfl_xor(v, 2, 64);
        v += __shfl_xor(v, 4, 64);
        v += __shfl_xor(v, 8, 64);
        if (ln == 0) l_s[w * 16 + quad * 4 + r] = v;
    }
    __syncthreads();

    float g = gamma[0];
    float rinv[4];
#pragma unroll
    for (int is = 0; is < 4; ++is) rinv[is] = g / l_s[is * 16 + ln];

    // epilogue: out = gamma*o/l + x*gate
#pragma unroll
    for (int cs = 0; cs < 4; ++cs) {
#pragma unroll
        for (int r = 0; r < 4; ++r) {
            int c = w * 64 + cs * 16 + quad * 4 + r;
            float gc = gate[b * CCH + c];
            size_t rowoff = (((size_t)(b * CCH + c)) << 12) + i0;
            float* po = out + rowoff;
            const float* px = x + rowoff;
#pragma unroll
            for (int is = 0; is < 4; ++is) {
                int idx = is * 16 + ln;
                po[idx] = acc[cs][is][r] * rinv[is] + px[idx] * gc;
            }
        }
    }
}

extern "C" void kernel_launch(void* const* d_in, const int* in_sizes, int n_in,
                              void* d_out, int out_size, void* d_ws, size_t ws_size,
                              hipStream_t stream) {
    const float* x = (const float*)d_in[0];
    const float* w1 = (const float*)d_in[1];
    const float* w2 = (const float*)d_in[2];
    const float* qw = (const float*)d_in[3];
    const float* qb = (const float*)d_in[4];
    const float* kw = (const float*)d_in[5];
    const float* kb = (const float*)d_in[6];
    const float* vw = (const float*)d_in[7];
    const float* vb = (const float*)d_in[8];
    const float* gamma = (const float*)d_in[9];
    float* out = (float*)d_out;
    char* ws = (char*)d_ws;

    float* avgp = (float*)(ws);                        // 8 KB
    float* maxp = (float*)(ws + 8192);                 // 8 KB
    float* gate = (float*)(ws + 16384);                // 8 KB
    unsigned short* Wb = (unsigned short*)(ws + 24576);               // 147456 B [288][256] bf16
    unsigned short* qT = (unsigned short*)(ws + 24576 + 147456);      // 1 MB [b][n][16]
    unsigned short* kT = (unsigned short*)(ws + 24576 + 147456 + 1048576);
    unsigned short* vB = (unsigned short*)(ws + 24576 + 147456 + 2097152);  // 16.8 MB [b][c][n]

    k_pool<<<2048, 256, 0, stream>>>(x, avgp, maxp);
    k_wprep<<<288, 256, 0, stream>>>(vw, qw, kw, Wb);
    k_gate<<<8, 256, 0, stream>>>(avgp, maxp, w1, w2, gate);
    k_proj<<<512, 256, 0, stream>>>(x, gate, Wb, vb, qb, kb, qT, kT, vB);
    k_attn<<<512, 256, 0, stream>>>(qT, kT, vB, x, gate, gamma, out);
}